// Round 7
// baseline (1545.351 us; speedup 1.0000x reference)
//
#include <hip/hip_runtime.h>
#include <hip/hip_bf16.h>
#include <stdint.h>
#include <stdio.h>

#define T_SEQ 4096
#define C_ST  1024
#define K3    3072
#define NB    4
#define NCHUNK 64
#define CHUNK  64

typedef __bf16 bf16x8_t __attribute__((ext_vector_type(8)));
typedef float f32x4_t __attribute__((ext_vector_type(4)));
typedef unsigned short u16x8 __attribute__((ext_vector_type(8)));
typedef unsigned short u16x4 __attribute__((ext_vector_type(4)));
typedef __attribute__((address_space(1))) unsigned int as1u32;
typedef __attribute__((address_space(3))) unsigned int as3u32;

__device__ __forceinline__ unsigned short bfbits(float f) {
  __hip_bfloat16 h = __float2bfloat16(f);
  return *reinterpret_cast<unsigned short*>(&h);
}
__device__ __forceinline__ float bf2f(unsigned short u) {
  __hip_bfloat16 h;
  *reinterpret_cast<unsigned short*>(&h) = u;
  return __bfloat162float(h);
}
__device__ __forceinline__ float phi_f(float x) {
  // silu(x) + 1
  return x / (1.0f + __expf(-x)) + 1.0f;
}

// ---------------------------------------------------------------------------
// Weight prep: W (1024x1024 f32) -> rows of K3=3072 bf16: [Wh | Wh | Wl]
// ---------------------------------------------------------------------------
__global__ __launch_bounds__(256) void conv_w_kernel(
    const float* __restrict__ Wq, const float* __restrict__ Wk,
    const float* __restrict__ Wv, const float* __restrict__ Wo,
    unsigned short* __restrict__ W3, unsigned short* __restrict__ Wo3) {
  int r = blockIdx.x;
  int which = blockIdx.y;
  const float* src = (which == 0) ? Wq : (which == 1) ? Wk : (which == 2) ? Wv : Wo;
  unsigned short* dst = (which < 3) ? (W3 + (size_t)(which * 1024 + r) * K3)
                                    : (Wo3 + (size_t)r * K3);
  int c4 = threadIdx.x * 4;
  float4 v = *reinterpret_cast<const float4*>(&src[(size_t)r * 1024 + c4]);
  float fe[4] = {v.x, v.y, v.z, v.w};
  u16x4 hh, ll;
#pragma unroll
  for (int e = 0; e < 4; ++e) {
    unsigned short hb = bfbits(fe[e]);
    hh[e] = hb;
    ll[e] = bfbits(fe[e] - bf2f(hb));
  }
  *reinterpret_cast<u16x4*>(&dst[c4])        = hh;
  *reinterpret_cast<u16x4*>(&dst[1024 + c4]) = hh;
  *reinterpret_cast<u16x4*>(&dst[2048 + c4]) = ll;
}

// ---------------------------------------------------------------------------
// x prep (one batch): x_b (C, T) f32 -> xT3_b (T, 3C) bf16 [xh | xl | xh]
// grid (T/64, C/64), 256 threads, 64x64 LDS tile
// ---------------------------------------------------------------------------
__global__ __launch_bounds__(256) void conv_x_kernel(
    const float* __restrict__ xb_, unsigned short* __restrict__ xT3) {
  __shared__ float tile[64][65];
  int c0 = blockIdx.y * 64, t0 = blockIdx.x * 64;
  const float* xb = xb_ + (size_t)c0 * T_SEQ + t0;
  int tid = threadIdx.x;
#pragma unroll
  for (int p = 0; p < 4; ++p) {
    int idx = tid + p * 256;
    int r = idx >> 4, q4 = (idx & 15) * 4;
    float4 v = *reinterpret_cast<const float4*>(&xb[(size_t)r * T_SEQ + q4]);
    tile[r][q4 + 0] = v.x; tile[r][q4 + 1] = v.y;
    tile[r][q4 + 2] = v.z; tile[r][q4 + 3] = v.w;
  }
  __syncthreads();
  int r = tid >> 2, q = (tid & 3) * 16;
  u16x8 h0, h1, l0, l1;
#pragma unroll
  for (int j = 0; j < 8; ++j) {
    float f = tile[q + j][r];
    unsigned short hb = bfbits(f);
    h0[j] = hb; l0[j] = bfbits(f - bf2f(hb));
  }
#pragma unroll
  for (int j = 0; j < 8; ++j) {
    float f = tile[q + 8 + j][r];
    unsigned short hb = bfbits(f);
    h1[j] = hb; l1[j] = bfbits(f - bf2f(hb));
  }
  unsigned short* dst = xT3 + ((size_t)(t0 + r)) * K3 + c0 + q;
  *reinterpret_cast<u16x8*>(dst)         = h0;
  *reinterpret_cast<u16x8*>(dst + 8)     = h1;
  *reinterpret_cast<u16x8*>(dst + 1024)  = l0;
  *reinterpret_cast<u16x8*>(dst + 1032)  = l1;
  *reinterpret_cast<u16x8*>(dst + 2048)  = h0;
  *reinterpret_cast<u16x8*>(dst + 2056)  = h1;
}

// ---------------------------------------------------------------------------
// gemm_bt: C[m][n] = sum_k A[m][k]*B[n][k]  (+ biasM[m] if given)
// 128x128 tile, BK=64, 4 waves (2x2), 16x16x32 MFMA, global_load_lds w16.
// LDS layout: 16B granules, granule g = kh*128 + row (kh = k-elems kh*8..+8).
//   -> fragment ds_read_b128: 16 lanes read consecutive granules = no bank
//      conflicts. Staging keeps linear LDS dest (wave-uniform base + lane*16)
//      with the granule mapping folded into the per-lane GLOBAL address.
// ---------------------------------------------------------------------------
__global__ __launch_bounds__(256) void gemm_bt_kernel(
    const unsigned short* __restrict__ A, const unsigned short* __restrict__ B,
    float* __restrict__ C, const float* __restrict__ biasM,
    int M, int N, int K) {
  __shared__ unsigned short As[128 * 64];
  __shared__ unsigned short Bs[128 * 64];
  int m0 = blockIdx.y * 128, n0 = blockIdx.x * 128;
  int tid = threadIdx.x, lane = tid & 63, wid = tid >> 6;
  int wr = wid >> 1, wc = wid & 1;
  int l16 = lane & 15, l4 = lane >> 4;
  f32x4_t acc[4][4] = {};

  for (int k0 = 0; k0 < K; k0 += 64) {
    __syncthreads();
#pragma unroll
    for (int s = 0; s < 4; ++s) {
      int c = wid * 4 + s;            // chunk 0..15 (1 KB each)
      int g = c * 64 + lane;          // granule 0..1023
      int kh = g >> 7, row = g & 127; // granule holds elems [kh*8, kh*8+8) of row
      const unsigned short* ga = A + (size_t)(m0 + row) * K + k0 + kh * 8;
      const unsigned short* gb = B + (size_t)(n0 + row) * K + k0 + kh * 8;
      __builtin_amdgcn_global_load_lds((as1u32*)ga, (as3u32*)(As + c * 512), 16, 0, 0);
      __builtin_amdgcn_global_load_lds((as1u32*)gb, (as3u32*)(Bs + c * 512), 16, 0, 0);
    }
    __syncthreads();
#pragma unroll
    for (int s2 = 0; s2 < 2; ++s2) {  // two 32-k sub-steps, frags reused
      bf16x8_t af[4], bfr[4];
      int kh = s2 * 4 + l4;
#pragma unroll
      for (int m = 0; m < 4; ++m)
        af[m] = *reinterpret_cast<const bf16x8_t*>(
            &As[(kh * 128 + (wr * 64 + m * 16 + l16)) * 8]);
#pragma unroll
      for (int n = 0; n < 4; ++n)
        bfr[n] = *reinterpret_cast<const bf16x8_t*>(
            &Bs[(kh * 128 + (wc * 64 + n * 16 + l16)) * 8]);
#pragma unroll
      for (int m = 0; m < 4; ++m)
#pragma unroll
        for (int n = 0; n < 4; ++n)
          acc[m][n] = __builtin_amdgcn_mfma_f32_16x16x32_bf16(af[m], bfr[n], acc[m][n], 0, 0, 0);
    }
  }

#pragma unroll
  for (int m = 0; m < 4; ++m) {
#pragma unroll
    for (int n = 0; n < 4; ++n) {
      int row = m0 + wr * 64 + m * 16 + l4 * 4;
      int col = n0 + wc * 64 + n * 16 + l16;
#pragma unroll
      for (int j = 0; j < 4; ++j) {
        float val = acc[m][n][j];
        if (biasM) val += biasM[row + j];
        C[(size_t)(row + j) * N + col] = val;
      }
    }
  }
}

// ---------------------------------------------------------------------------
// Scan phase A (one batch): per-chunk totals of phi_k and phi_k*v
// grid (NCHUNK/4, 16), 256 threads = 4 waves, wave w handles chunk bx*4+w
// ---------------------------------------------------------------------------
__global__ __launch_bounds__(256) void scan_a_kernel(
    const float* __restrict__ qkvT, const float* __restrict__ bv,
    float* __restrict__ partK, float* __restrict__ partKV) {
  int d = threadIdx.x & 63;
  int w = threadIdx.x >> 6;
  int ch = blockIdx.x * 4 + w, h = blockIdx.y;
  int c = h * 64 + d;
  float bvc = bv[c];
  const float* base = qkvT + (size_t)ch * CHUNK * K3;
  float sk = 0.f, skv = 0.f;
  for (int tt = 0; tt < CHUNK; ++tt) {
    const float* row = base + (size_t)tt * K3;
    float kv = row[1024 + c];
    float vv = row[2048 + c] + bvc;
    float pk = phi_f(kv);
    sk += pk; skv += pk * vv;
  }
  size_t pidx = ((size_t)h * NCHUNK + ch) * 64 + d;
  partK[pidx] = sk;
  partKV[pidx] = skv;
}

// Phase B: exclusive prefix over chunks. grid (16 H), 64 threads.
__global__ void scan_b_kernel(float* __restrict__ partK, float* __restrict__ partKV) {
  int d = threadIdx.x;
  int h = blockIdx.x;
  size_t base = (size_t)h * NCHUNK * 64 + d;
  float rk = 0.f, rkv = 0.f;
  for (int ch = 0; ch < NCHUNK; ++ch) {
    size_t i = base + (size_t)ch * 64;
    float tk = partK[i], tkv = partKV[i];
    partK[i] = rk; partKV[i] = rkv;
    rk += tk; rkv += tkv;
  }
}

// Phase C: emit attention output, split hi/lo bf16, t-major [oh | ol | oh]
// grid (NCHUNK/4, 16), 256 threads = 4 waves (one chunk per wave)
__global__ __launch_bounds__(256) void scan_c_kernel(
    const float* __restrict__ qkvT,
    const float* __restrict__ bq, const float* __restrict__ bv,
    const float* __restrict__ partK, const float* __restrict__ partKV,
    unsigned short* __restrict__ outT3) {
  int d = threadIdx.x & 63;
  int w = threadIdx.x >> 6;
  int ch = blockIdx.x * 4 + w, h = blockIdx.y;
  int c = h * 64 + d;
  size_t pidx = ((size_t)h * NCHUNK + ch) * 64 + d;
  float sk = partK[pidx], skv = partKV[pidx];
  float bqc = bq[c], bvc = bv[c];
  const float* base = qkvT + (size_t)ch * CHUNK * K3;
  unsigned short* obase = outT3 + (size_t)ch * CHUNK * K3;
  for (int tt = 0; tt < CHUNK; ++tt) {
    const float* row = base + (size_t)tt * K3;
    float qv = row[c] + bqc;
    float kv = row[1024 + c];
    float vv = row[2048 + c] + bvc;
    float pq = phi_f(qv), pk = phi_f(kv);
    sk += pk; skv += pk * vv;
    float dp = pq * sk;
#pragma unroll
    for (int off = 32; off > 0; off >>= 1) dp += __shfl_xor(dp, off);
    float den = dp + 1e-6f;
    float o = pq * skv / den * 0.125f;  // 1/sqrt(64)
    unsigned short oh = bfbits(o);
    unsigned short ol = bfbits(o - bf2f(oh));
    unsigned short* orow = obase + (size_t)tt * K3;
    orow[c] = oh; orow[1024 + c] = ol; orow[2048 + c] = oh;
  }
}

// ---------------------------------------------------------------------------
extern "C" void kernel_launch(void* const* d_in, const int* in_sizes, int n_in,
                              void* d_out, int out_size, void* d_ws, size_t ws_size,
                              hipStream_t stream) {
  const float* x  = (const float*)d_in[0];
  const float* Wq = (const float*)d_in[1];
  const float* bq = (const float*)d_in[2];
  const float* Wk = (const float*)d_in[3];
  const float* Wv = (const float*)d_in[4];
  const float* bv = (const float*)d_in[5];
  const float* Wo = (const float*)d_in[6];
  const float* bo = (const float*)d_in[7];
  float* out = (float*)d_out;

  // Per-batch workspace layout (bytes): peak 101,187,584
  const size_t REQUIRED = 101187584;
  fprintf(stderr, "kernel_launch: ws_size=%zu required=%zu\n", ws_size, REQUIRED);
  if (ws_size < REQUIRED) return;

  char* w = (char*)d_ws;
  unsigned short* W3     = (unsigned short*)(w);                 // 18,874,368
  unsigned short* Wo3    = (unsigned short*)(w + 18874368);      //  6,291,456
  unsigned short* xT3b   = (unsigned short*)(w + 25165824);      // 25,165,824
  float*          qkvTb  = (float*)(w + 50331648);               // 50,331,648
  float*          partK  = (float*)(w + 100663296);              //    262,144
  float*          partKV = (float*)(w + 100925440);              //    262,144

  // 1) weight prep (once)
  conv_w_kernel<<<dim3(1024, 4), 256, 0, stream>>>(Wq, Wk, Wv, Wo, W3, Wo3);

  for (int b = 0; b < NB; ++b) {
    const float* xb = x + (size_t)b * C_ST * T_SEQ;
    float* outb = out + (size_t)b * C_ST * T_SEQ;
    // 2) x transpose + split (batch b)
    conv_x_kernel<<<dim3(T_SEQ / 64, C_ST / 64), 256, 0, stream>>>(xb, xT3b);
    // 3) fused QKV GEMM: qkvTb[t][j] = sum_k xT3b[t][k] * W3[j][k]
    gemm_bt_kernel<<<dim3(K3 / 128, T_SEQ / 128), 256, 0, stream>>>(
        xT3b, W3, qkvTb, nullptr, T_SEQ, K3, K3);
    // 4) chunked scan (batch b); scan_c overwrites xT3b with attention output
    scan_a_kernel<<<dim3(NCHUNK / 4, 16), 256, 0, stream>>>(qkvTb, bv, partK, partKV);
    scan_b_kernel<<<dim3(16), 64, 0, stream>>>(partK, partKV);
    scan_c_kernel<<<dim3(NCHUNK / 4, 16), 256, 0, stream>>>(qkvTb, bq, bv, partK, partKV, xT3b);
    // 5) output GEMM: outb[o][t] = bo[o] + sum_k Wo3[o][k] * xT3b[t][k]
    gemm_bt_kernel<<<dim3(T_SEQ / 128, C_ST / 128), 256, 0, stream>>>(
        Wo3, xT3b, outb, bo, C_ST, T_SEQ, K3);
  }
}

// Round 11
// 1040.612 us; speedup vs baseline: 1.4850x; 1.4850x over previous
//
#include <hip/hip_runtime.h>
#include <hip/hip_bf16.h>
#include <stdint.h>
#include <stdio.h>

#define T_SEQ 4096
#define C_ST  1024
#define K3    3072
#define NB    4
#define NCHUNK 64
#define CHUNK  64

typedef __bf16 bf16x8_t __attribute__((ext_vector_type(8)));
typedef float f32x4_t __attribute__((ext_vector_type(4)));
typedef unsigned short u16x8 __attribute__((ext_vector_type(8)));
typedef unsigned short u16x4 __attribute__((ext_vector_type(4)));
typedef __attribute__((address_space(1))) unsigned int as1u32;
typedef __attribute__((address_space(3))) unsigned int as3u32;

__device__ __forceinline__ unsigned short bfbits(float f) {
  __hip_bfloat16 h = __float2bfloat16(f);
  return *reinterpret_cast<unsigned short*>(&h);
}
__device__ __forceinline__ float bf2f(unsigned short u) {
  __hip_bfloat16 h;
  *reinterpret_cast<unsigned short*>(&h) = u;
  return __bfloat162float(h);
}
__device__ __forceinline__ float phi_f(float x) {
  // silu(x) + 1
  return x / (1.0f + __expf(-x)) + 1.0f;
}

// ---------------------------------------------------------------------------
// Weight prep: W (1024x1024 f32) -> rows of K3=3072 bf16: [Wh | Wh | Wl]
// ---------------------------------------------------------------------------
__global__ __launch_bounds__(256) void conv_w_kernel(
    const float* __restrict__ Wq, const float* __restrict__ Wk,
    const float* __restrict__ Wv, const float* __restrict__ Wo,
    unsigned short* __restrict__ W3, unsigned short* __restrict__ Wo3) {
  int r = blockIdx.x;
  int which = blockIdx.y;
  const float* src = (which == 0) ? Wq : (which == 1) ? Wk : (which == 2) ? Wv : Wo;
  unsigned short* dst = (which < 3) ? (W3 + (size_t)(which * 1024 + r) * K3)
                                    : (Wo3 + (size_t)r * K3);
  int c4 = threadIdx.x * 4;
  float4 v = *reinterpret_cast<const float4*>(&src[(size_t)r * 1024 + c4]);
  float fe[4] = {v.x, v.y, v.z, v.w};
  u16x4 hh, ll;
#pragma unroll
  for (int e = 0; e < 4; ++e) {
    unsigned short hb = bfbits(fe[e]);
    hh[e] = hb;
    ll[e] = bfbits(fe[e] - bf2f(hb));
  }
  *reinterpret_cast<u16x4*>(&dst[c4])        = hh;
  *reinterpret_cast<u16x4*>(&dst[1024 + c4]) = hh;
  *reinterpret_cast<u16x4*>(&dst[2048 + c4]) = ll;
}

// ---------------------------------------------------------------------------
// x prep (one batch): x_b (C, T) f32 -> xT3_b (T, 3C) bf16 [xh | xl | xh]
// ---------------------------------------------------------------------------
__global__ __launch_bounds__(256) void conv_x_kernel(
    const float* __restrict__ xb_, unsigned short* __restrict__ xT3) {
  __shared__ float tile[64][65];
  int c0 = blockIdx.y * 64, t0 = blockIdx.x * 64;
  const float* xb = xb_ + (size_t)c0 * T_SEQ + t0;
  int tid = threadIdx.x;
#pragma unroll
  for (int p = 0; p < 4; ++p) {
    int idx = tid + p * 256;
    int r = idx >> 4, q4 = (idx & 15) * 4;
    float4 v = *reinterpret_cast<const float4*>(&xb[(size_t)r * T_SEQ + q4]);
    tile[r][q4 + 0] = v.x; tile[r][q4 + 1] = v.y;
    tile[r][q4 + 2] = v.z; tile[r][q4 + 3] = v.w;
  }
  __syncthreads();
  int r = tid >> 2, q = (tid & 3) * 16;
  u16x8 h0, h1, l0, l1;
#pragma unroll
  for (int j = 0; j < 8; ++j) {
    float f = tile[q + j][r];
    unsigned short hb = bfbits(f);
    h0[j] = hb; l0[j] = bfbits(f - bf2f(hb));
  }
#pragma unroll
  for (int j = 0; j < 8; ++j) {
    float f = tile[q + 8 + j][r];
    unsigned short hb = bfbits(f);
    h1[j] = hb; l1[j] = bfbits(f - bf2f(hb));
  }
  unsigned short* dst = xT3 + ((size_t)(t0 + r)) * K3 + c0 + q;
  *reinterpret_cast<u16x8*>(dst)         = h0;
  *reinterpret_cast<u16x8*>(dst + 8)     = h1;
  *reinterpret_cast<u16x8*>(dst + 1024)  = l0;
  *reinterpret_cast<u16x8*>(dst + 1032)  = l1;
  *reinterpret_cast<u16x8*>(dst + 2048)  = h0;
  *reinterpret_cast<u16x8*>(dst + 2056)  = h1;
}

// ---------------------------------------------------------------------------
// gemm_bt: C[m][n] = sum_k A[m][k]*B[n][k]  (+ biasM[m] if given)
// 128x128 tile, BK=32, 4 waves (2x2), 16x16x32 MFMA, global_load_lds w16.
// Bank-conflict fix (rule #21, both-sides): LDS dest stays LINEAR
// (wave-uniform base + lane*16) and each wave's global footprint stays the
// SAME contiguous 1KB; we only permute WHICH lane fetches which 16B segment:
//   stage:  kb_src = (lane&3) ^ ((lane>>3)&3)        [lane permutation]
//   read :  kidx   = l4 ^ ((l16>>1)&3)               [same involution]
// Quarter-wave read banks become {0,16,4,20,8,24,12,28} -> 2-way = free.
// ---------------------------------------------------------------------------
__global__ __launch_bounds__(256) void gemm_bt_kernel(
    const unsigned short* __restrict__ A, const unsigned short* __restrict__ B,
    float* __restrict__ C, const float* __restrict__ biasM,
    int M, int N, int K) {
  __shared__ unsigned short As[128 * 32];
  __shared__ unsigned short Bs[128 * 32];
  int m0 = blockIdx.y * 128, n0 = blockIdx.x * 128;
  int tid = threadIdx.x, lane = tid & 63, wid = tid >> 6;
  int wr = wid >> 1, wc = wid & 1;
  int l16 = lane & 15, l4 = lane >> 4;
  int sw_r = (l16 >> 1) & 3;                 // read-side swizzle
  int kb_src = (lane & 3) ^ ((lane >> 3) & 3);  // stage-side swizzle
  f32x4_t acc[4][4] = {};

  for (int k0 = 0; k0 < K; k0 += 32) {
    __syncthreads();
#pragma unroll
    for (int s = 0; s < 2; ++s) {
      int chunk = wid * 2 + s;                // 1KB chunks, 8 per tile
      int row = chunk * 16 + (lane >> 2);     // 16 rows per chunk
      const unsigned short* ga = A + (size_t)(m0 + row) * K + k0 + kb_src * 8;
      const unsigned short* gb = B + (size_t)(n0 + row) * K + k0 + kb_src * 8;
      __builtin_amdgcn_global_load_lds((as1u32*)ga, (as3u32*)(As + chunk * 512), 16, 0, 0);
      __builtin_amdgcn_global_load_lds((as1u32*)gb, (as3u32*)(Bs + chunk * 512), 16, 0, 0);
    }
    __syncthreads();
    bf16x8_t af[4], bfr[4];
    int kidx = l4 ^ sw_r;
#pragma unroll
    for (int m = 0; m < 4; ++m)
      af[m] = *reinterpret_cast<const bf16x8_t*>(
          &As[(wr * 64 + m * 16 + l16) * 32 + kidx * 8]);
#pragma unroll
    for (int n = 0; n < 4; ++n)
      bfr[n] = *reinterpret_cast<const bf16x8_t*>(
          &Bs[(wc * 64 + n * 16 + l16) * 32 + kidx * 8]);
#pragma unroll
    for (int m = 0; m < 4; ++m)
#pragma unroll
      for (int n = 0; n < 4; ++n)
        acc[m][n] = __builtin_amdgcn_mfma_f32_16x16x32_bf16(af[m], bfr[n], acc[m][n], 0, 0, 0);
  }

#pragma unroll
  for (int m = 0; m < 4; ++m) {
#pragma unroll
    for (int n = 0; n < 4; ++n) {
      int row = m0 + wr * 64 + m * 16 + l4 * 4;
      int col = n0 + wc * 64 + n * 16 + l16;
#pragma unroll
      for (int j = 0; j < 4; ++j) {
        float val = acc[m][n][j];
        if (biasM) val += biasM[row + j];
        C[(size_t)(row + j) * N + col] = val;
      }
    }
  }
}

// ---------------------------------------------------------------------------
// Scan phase A (one batch): per-chunk totals of phi_k and phi_k*v
// grid (NCHUNK/4, 16), 256 threads = 4 waves, wave w -> chunk bx*4+w.
// 4x unrolled: batch loads (ILP hides HBM latency), then accumulate.
// ---------------------------------------------------------------------------
__global__ __launch_bounds__(256) void scan_a_kernel(
    const float* __restrict__ qkvT, const float* __restrict__ bv,
    float* __restrict__ partK, float* __restrict__ partKV) {
  int d = threadIdx.x & 63;
  int w = threadIdx.x >> 6;
  int ch = blockIdx.x * 4 + w, h = blockIdx.y;
  int c = h * 64 + d;
  float bvc = bv[c];
  const float* base = qkvT + (size_t)ch * CHUNK * K3;
  float sk = 0.f, skv = 0.f;
  for (int tt = 0; tt < CHUNK; tt += 4) {
    float kv[4], vv[4];
#pragma unroll
    for (int u = 0; u < 4; ++u) {
      const float* row = base + (size_t)(tt + u) * K3;
      kv[u] = row[1024 + c];
      vv[u] = row[2048 + c];
    }
#pragma unroll
    for (int u = 0; u < 4; ++u) {
      float pk = phi_f(kv[u]);
      sk += pk; skv += pk * (vv[u] + bvc);
    }
  }
  size_t pidx = ((size_t)h * NCHUNK + ch) * 64 + d;
  partK[pidx] = sk;
  partKV[pidx] = skv;
}

// Phase B: exclusive prefix over chunks. grid (16 H), 64 threads.
__global__ void scan_b_kernel(float* __restrict__ partK, float* __restrict__ partKV) {
  int d = threadIdx.x;
  int h = blockIdx.x;
  size_t base = (size_t)h * NCHUNK * 64 + d;
  float rk = 0.f, rkv = 0.f;
  for (int ch = 0; ch < NCHUNK; ++ch) {
    size_t i = base + (size_t)ch * 64;
    float tk = partK[i], tkv = partKV[i];
    partK[i] = rk; partKV[i] = rkv;
    rk += tk; rkv += tkv;
  }
}

// Phase C: emit attention output, split hi/lo bf16, t-major [oh | ol | oh]
// grid (NCHUNK/4, 16), 256 threads = 4 waves. 4x unrolled: batched loads,
// snapshot sums per-t, 4 interleaved 6-step shuffle reductions.
__global__ __launch_bounds__(256) void scan_c_kernel(
    const float* __restrict__ qkvT,
    const float* __restrict__ bq, const float* __restrict__ bv,
    const float* __restrict__ partK, const float* __restrict__ partKV,
    unsigned short* __restrict__ outT3) {
  int d = threadIdx.x & 63;
  int w = threadIdx.x >> 6;
  int ch = blockIdx.x * 4 + w, h = blockIdx.y;
  int c = h * 64 + d;
  size_t pidx = ((size_t)h * NCHUNK + ch) * 64 + d;
  float sk = partK[pidx], skv = partKV[pidx];
  float bqc = bq[c], bvc = bv[c];
  const float* base = qkvT + (size_t)ch * CHUNK * K3;
  unsigned short* obase = outT3 + (size_t)ch * CHUNK * K3;
  for (int tt = 0; tt < CHUNK; tt += 4) {
    float qv[4], kv[4], vv[4];
#pragma unroll
    for (int u = 0; u < 4; ++u) {
      const float* row = base + (size_t)(tt + u) * K3;
      qv[u] = row[c];
      kv[u] = row[1024 + c];
      vv[u] = row[2048 + c];
    }
    float pq[4], dp[4], skv_s[4];
#pragma unroll
    for (int u = 0; u < 4; ++u) {
      pq[u] = phi_f(qv[u] + bqc);
      float pk = phi_f(kv[u]);
      sk += pk; skv += pk * (vv[u] + bvc);
      dp[u] = pq[u] * sk;
      skv_s[u] = skv;
    }
#pragma unroll
    for (int off = 32; off > 0; off >>= 1)
#pragma unroll
      for (int u = 0; u < 4; ++u) dp[u] += __shfl_xor(dp[u], off);
#pragma unroll
    for (int u = 0; u < 4; ++u) {
      float o = pq[u] * skv_s[u] / (dp[u] + 1e-6f) * 0.125f;  // 1/sqrt(64)
      unsigned short oh = bfbits(o);
      unsigned short ol = bfbits(o - bf2f(oh));
      unsigned short* orow = obase + (size_t)(tt + u) * K3;
      orow[c] = oh; orow[1024 + c] = ol; orow[2048 + c] = oh;
    }
  }
}

// ---------------------------------------------------------------------------
extern "C" void kernel_launch(void* const* d_in, const int* in_sizes, int n_in,
                              void* d_out, int out_size, void* d_ws, size_t ws_size,
                              hipStream_t stream) {
  const float* x  = (const float*)d_in[0];
  const float* Wq = (const float*)d_in[1];
  const float* bq = (const float*)d_in[2];
  const float* Wk = (const float*)d_in[3];
  const float* Wv = (const float*)d_in[4];
  const float* bv = (const float*)d_in[5];
  const float* Wo = (const float*)d_in[6];
  const float* bo = (const float*)d_in[7];
  float* out = (float*)d_out;

  // Per-batch workspace layout (bytes): peak 101,187,584 (proven to fit)
  const size_t REQUIRED = 101187584;
  fprintf(stderr, "kernel_launch: ws_size=%zu required=%zu\n", ws_size, REQUIRED);
  if (ws_size < REQUIRED) return;

  char* w = (char*)d_ws;
  unsigned short* W3     = (unsigned short*)(w);                 // 18,874,368
  unsigned short* Wo3    = (unsigned short*)(w + 18874368);      //  6,291,456
  unsigned short* xT3b   = (unsigned short*)(w + 25165824);      // 25,165,824
  float*          qkvTb  = (float*)(w + 50331648);               // 50,331,648
  float*          partK  = (float*)(w + 100663296);              //    262,144
  float*          partKV = (float*)(w + 100925440);              //    262,144

  // 1) weight prep (once)
  conv_w_kernel<<<dim3(1024, 4), 256, 0, stream>>>(Wq, Wk, Wv, Wo, W3, Wo3);

  for (int b = 0; b < NB; ++b) {
    const float* xb = x + (size_t)b * C_ST * T_SEQ;
    float* outb = out + (size_t)b * C_ST * T_SEQ;
    // 2) x transpose + split (batch b)
    conv_x_kernel<<<dim3(T_SEQ / 64, C_ST / 64), 256, 0, stream>>>(xb, xT3b);
    // 3) fused QKV GEMM: qkvTb[t][j] = sum_k xT3b[t][k] * W3[j][k]
    gemm_bt_kernel<<<dim3(K3 / 128, T_SEQ / 128), 256, 0, stream>>>(
        xT3b, W3, qkvTb, nullptr, T_SEQ, K3, K3);
    // 4) chunked scan (batch b); scan_c overwrites xT3b with attention output
    scan_a_kernel<<<dim3(NCHUNK / 4, 16), 256, 0, stream>>>(qkvTb, bv, partK, partKV);
    scan_b_kernel<<<dim3(16), 64, 0, stream>>>(partK, partKV);
    scan_c_kernel<<<dim3(NCHUNK / 4, 16), 256, 0, stream>>>(qkvTb, bq, bv, partK, partKV, xT3b);
    // 5) output GEMM: outb[o][t] = bo[o] + sum_k Wo3[o][k] * xT3b[t][k]
    gemm_bt_kernel<<<dim3(T_SEQ / 128, C_ST / 128), 256, 0, stream>>>(
        Wo3, xT3b, outb, bo, C_ST, T_SEQ, K3);
  }
}

// Round 12
// 857.972 us; speedup vs baseline: 1.8012x; 1.2129x over previous
//
#include <hip/hip_runtime.h>
#include <hip/hip_bf16.h>
#include <stdint.h>

#define T_SEQ 4096
#define C_ST  1024
#define K2    2048
#define K3    3072
#define NB    4
#define NCHUNK 64
#define CHUNK  64

typedef __bf16 bf16x8_t __attribute__((ext_vector_type(8)));
typedef float f32x4_t __attribute__((ext_vector_type(4)));
typedef unsigned short u16x8 __attribute__((ext_vector_type(8)));
typedef unsigned short u16x4 __attribute__((ext_vector_type(4)));
typedef __attribute__((address_space(1))) unsigned int as1u32;
typedef __attribute__((address_space(3))) unsigned int as3u32;

__device__ __forceinline__ unsigned short bfbits(float f) {
  __hip_bfloat16 h = __float2bfloat16(f);
  return *reinterpret_cast<unsigned short*>(&h);
}
__device__ __forceinline__ float bf2f(unsigned short u) {
  __hip_bfloat16 h;
  *reinterpret_cast<unsigned short*>(&h) = u;
  return __bfloat162float(h);
}
__device__ __forceinline__ float phi_f(float x) {
  // silu(x) + 1
  return x / (1.0f + __expf(-x)) + 1.0f;
}

// ---------------------------------------------------------------------------
// Weight prep.
//  which<3 (Wq,Wk,Wv): -> W3 rows of K2=2048 bf16: [Wh | Wh]
//    (pairs with activations [xh | xl]: xh*Wh + xl*Wh = x*Wh)
//  which==3 (Wo):      -> Wo3 rows of K3=3072 bf16: [Wh | Wh | Wl]
//    (pairs with [oh | ol | oh]: full 3-term split, kept for final precision)
// ---------------------------------------------------------------------------
__global__ __launch_bounds__(256) void conv_w_kernel(
    const float* __restrict__ Wq, const float* __restrict__ Wk,
    const float* __restrict__ Wv, const float* __restrict__ Wo,
    unsigned short* __restrict__ W3, unsigned short* __restrict__ Wo3) {
  int r = blockIdx.x;
  int which = blockIdx.y;
  const float* src = (which == 0) ? Wq : (which == 1) ? Wk : (which == 2) ? Wv : Wo;
  int c4 = threadIdx.x * 4;
  float4 v = *reinterpret_cast<const float4*>(&src[(size_t)r * 1024 + c4]);
  float fe[4] = {v.x, v.y, v.z, v.w};
  u16x4 hh, ll;
#pragma unroll
  for (int e = 0; e < 4; ++e) {
    unsigned short hb = bfbits(fe[e]);
    hh[e] = hb;
    ll[e] = bfbits(fe[e] - bf2f(hb));
  }
  if (which < 3) {
    unsigned short* dst = W3 + (size_t)(which * 1024 + r) * K2;
    *reinterpret_cast<u16x4*>(&dst[c4])        = hh;
    *reinterpret_cast<u16x4*>(&dst[1024 + c4]) = hh;
  } else {
    unsigned short* dst = Wo3 + (size_t)r * K3;
    *reinterpret_cast<u16x4*>(&dst[c4])        = hh;
    *reinterpret_cast<u16x4*>(&dst[1024 + c4]) = hh;
    *reinterpret_cast<u16x4*>(&dst[2048 + c4]) = ll;
  }
}

// ---------------------------------------------------------------------------
// x prep (one batch): x_b (C, T) f32 -> xT3_b (T, 2C) bf16 [xh | xl]
// ---------------------------------------------------------------------------
__global__ __launch_bounds__(256) void conv_x_kernel(
    const float* __restrict__ xb_, unsigned short* __restrict__ xT3) {
  __shared__ float tile[64][65];
  int c0 = blockIdx.y * 64, t0 = blockIdx.x * 64;
  const float* xb = xb_ + (size_t)c0 * T_SEQ + t0;
  int tid = threadIdx.x;
#pragma unroll
  for (int p = 0; p < 4; ++p) {
    int idx = tid + p * 256;
    int r = idx >> 4, q4 = (idx & 15) * 4;
    float4 v = *reinterpret_cast<const float4*>(&xb[(size_t)r * T_SEQ + q4]);
    tile[r][q4 + 0] = v.x; tile[r][q4 + 1] = v.y;
    tile[r][q4 + 2] = v.z; tile[r][q4 + 3] = v.w;
  }
  __syncthreads();
  int r = tid >> 2, q = (tid & 3) * 16;
  u16x8 h0, h1, l0, l1;
#pragma unroll
  for (int j = 0; j < 8; ++j) {
    float f = tile[q + j][r];
    unsigned short hb = bfbits(f);
    h0[j] = hb; l0[j] = bfbits(f - bf2f(hb));
  }
#pragma unroll
  for (int j = 0; j < 8; ++j) {
    float f = tile[q + 8 + j][r];
    unsigned short hb = bfbits(f);
    h1[j] = hb; l1[j] = bfbits(f - bf2f(hb));
  }
  unsigned short* dst = xT3 + ((size_t)(t0 + r)) * K2 + c0 + q;
  *reinterpret_cast<u16x8*>(dst)         = h0;
  *reinterpret_cast<u16x8*>(dst + 8)     = h1;
  *reinterpret_cast<u16x8*>(dst + 1024)  = l0;
  *reinterpret_cast<u16x8*>(dst + 1032)  = l1;
}

// ---------------------------------------------------------------------------
// gemm_bt: C[m][n] = sum_k A[m][k]*B[n][k]  (+ biasM[m] if given)
// 128x128 tile, BK=64, 4 waves (2x2), 16x16x32 MFMA, global_load_lds w16.
// LDS rows are 128B = 8 x 16B segments. Lane-permutation swizzle (rule #21):
//   stage: chunk = 1KB = rows 8c..8c+7; lane (g=l>>3, s=l&7) fetches
//          global segment  seg_src = s ^ g  of row 8c+g  -> LDS linear.
//          => LDS[row][seg] holds A[row][seg ^ (row&7)].
//   read : segment  kseg ^ (row&7)  recovers A[row][kseg].
//   Banks: 8 groups x 2-way (free); staging stays contiguous-128B/8-lanes.
// BK=64 => one barrier pair per 64 K-elems (3x fewer than BK=32).
// ---------------------------------------------------------------------------
__global__ __launch_bounds__(256) void gemm_bt_kernel(
    const unsigned short* __restrict__ A, const unsigned short* __restrict__ B,
    float* __restrict__ C, const float* __restrict__ biasM,
    int M, int N, int K) {
  __shared__ unsigned short As[128 * 64];
  __shared__ unsigned short Bs[128 * 64];
  int m0 = blockIdx.y * 128, n0 = blockIdx.x * 128;
  int tid = threadIdx.x, lane = tid & 63, wid = tid >> 6;
  int wr = wid >> 1, wc = wid & 1;
  int l16 = lane & 15, l4 = lane >> 4;
  int seg_src = (lane & 7) ^ ((lane >> 3) & 7);  // stage-side lane permutation
  f32x4_t acc[4][4] = {};

  for (int k0 = 0; k0 < K; k0 += 64) {
    __syncthreads();
#pragma unroll
    for (int s = 0; s < 4; ++s) {
      int chunk = wid * 4 + s;              // 0..15, 1KB each = rows 8c..8c+7
      int row = chunk * 8 + (lane >> 3);
      const unsigned short* ga = A + (size_t)(m0 + row) * K + k0 + seg_src * 8;
      const unsigned short* gb = B + (size_t)(n0 + row) * K + k0 + seg_src * 8;
      __builtin_amdgcn_global_load_lds((as1u32*)ga, (as3u32*)(As + chunk * 512), 16, 0, 0);
      __builtin_amdgcn_global_load_lds((as1u32*)gb, (as3u32*)(Bs + chunk * 512), 16, 0, 0);
    }
    __syncthreads();
#pragma unroll
    for (int s2 = 0; s2 < 2; ++s2) {        // two 32-k sub-steps
      bf16x8_t af[4], bfr[4];
      int kseg = s2 * 4 + l4;
#pragma unroll
      for (int m = 0; m < 4; ++m) {
        int r = wr * 64 + m * 16 + l16;
        af[m] = *reinterpret_cast<const bf16x8_t*>(
            &As[r * 64 + (kseg ^ (r & 7)) * 8]);
      }
#pragma unroll
      for (int n = 0; n < 4; ++n) {
        int r = wc * 64 + n * 16 + l16;
        bfr[n] = *reinterpret_cast<const bf16x8_t*>(
            &Bs[r * 64 + (kseg ^ (r & 7)) * 8]);
      }
#pragma unroll
      for (int m = 0; m < 4; ++m)
#pragma unroll
        for (int n = 0; n < 4; ++n)
          acc[m][n] = __builtin_amdgcn_mfma_f32_16x16x32_bf16(af[m], bfr[n], acc[m][n], 0, 0, 0);
    }
  }

#pragma unroll
  for (int m = 0; m < 4; ++m) {
#pragma unroll
    for (int n = 0; n < 4; ++n) {
      int row = m0 + wr * 64 + m * 16 + l4 * 4;
      int col = n0 + wc * 64 + n * 16 + l16;
#pragma unroll
      for (int j = 0; j < 4; ++j) {
        float val = acc[m][n][j];
        if (biasM) val += biasM[row + j];
        C[(size_t)(row + j) * N + col] = val;
      }
    }
  }
}

// ---------------------------------------------------------------------------
// Scan phase A (one batch): per-chunk totals of phi_k and phi_k*v
// grid (NCHUNK/4, 16), 256 threads = 4 waves, wave w -> chunk bx*4+w.
// ---------------------------------------------------------------------------
__global__ __launch_bounds__(256) void scan_a_kernel(
    const float* __restrict__ qkvT, const float* __restrict__ bv,
    float* __restrict__ partK, float* __restrict__ partKV) {
  int d = threadIdx.x & 63;
  int w = threadIdx.x >> 6;
  int ch = blockIdx.x * 4 + w, h = blockIdx.y;
  int c = h * 64 + d;
  float bvc = bv[c];
  const float* base = qkvT + (size_t)ch * CHUNK * K3;
  float sk = 0.f, skv = 0.f;
  for (int tt = 0; tt < CHUNK; tt += 4) {
    float kv[4], vv[4];
#pragma unroll
    for (int u = 0; u < 4; ++u) {
      const float* row = base + (size_t)(tt + u) * K3;
      kv[u] = row[1024 + c];
      vv[u] = row[2048 + c];
    }
#pragma unroll
    for (int u = 0; u < 4; ++u) {
      float pk = phi_f(kv[u]);
      sk += pk; skv += pk * (vv[u] + bvc);
    }
  }
  size_t pidx = ((size_t)h * NCHUNK + ch) * 64 + d;
  partK[pidx] = sk;
  partKV[pidx] = skv;
}

// Phase B: exclusive prefix over chunks. grid (16 H), 64 threads.
__global__ void scan_b_kernel(float* __restrict__ partK, float* __restrict__ partKV) {
  int d = threadIdx.x;
  int h = blockIdx.x;
  size_t base = (size_t)h * NCHUNK * 64 + d;
  float rk = 0.f, rkv = 0.f;
  for (int ch = 0; ch < NCHUNK; ++ch) {
    size_t i = base + (size_t)ch * 64;
    float tk = partK[i], tkv = partKV[i];
    partK[i] = rk; partKV[i] = rkv;
    rk += tk; rkv += tkv;
  }
}

// Phase C: emit attention output, split hi/lo bf16, t-major [oh | ol | oh]
// (stride K3 — GEMM2 keeps the full 3-term split for final precision)
__global__ __launch_bounds__(256) void scan_c_kernel(
    const float* __restrict__ qkvT,
    const float* __restrict__ bq, const float* __restrict__ bv,
    const float* __restrict__ partK, const float* __restrict__ partKV,
    unsigned short* __restrict__ outT3) {
  int d = threadIdx.x & 63;
  int w = threadIdx.x >> 6;
  int ch = blockIdx.x * 4 + w, h = blockIdx.y;
  int c = h * 64 + d;
  size_t pidx = ((size_t)h * NCHUNK + ch) * 64 + d;
  float sk = partK[pidx], skv = partKV[pidx];
  float bqc = bq[c], bvc = bv[c];
  const float* base = qkvT + (size_t)ch * CHUNK * K3;
  unsigned short* obase = outT3 + (size_t)ch * CHUNK * K3;
  for (int tt = 0; tt < CHUNK; tt += 4) {
    float qv[4], kv[4], vv[4];
#pragma unroll
    for (int u = 0; u < 4; ++u) {
      const float* row = base + (size_t)(tt + u) * K3;
      qv[u] = row[c];
      kv[u] = row[1024 + c];
      vv[u] = row[2048 + c];
    }
    float pq[4], dp[4], skv_s[4];
#pragma unroll
    for (int u = 0; u < 4; ++u) {
      pq[u] = phi_f(qv[u] + bqc);
      float pk = phi_f(kv[u]);
      sk += pk; skv += pk * (vv[u] + bvc);
      dp[u] = pq[u] * sk;
      skv_s[u] = skv;
    }
#pragma unroll
    for (int off = 32; off > 0; off >>= 1)
#pragma unroll
      for (int u = 0; u < 4; ++u) dp[u] += __shfl_xor(dp[u], off);
#pragma unroll
    for (int u = 0; u < 4; ++u) {
      float o = pq[u] * skv_s[u] / (dp[u] + 1e-6f) * 0.125f;  // 1/sqrt(64)
      unsigned short oh = bfbits(o);
      unsigned short ol = bfbits(o - bf2f(oh));
      unsigned short* orow = obase + (size_t)(tt + u) * K3;
      orow[c] = oh; orow[1024 + c] = ol; orow[2048 + c] = oh;
    }
  }
}

// ---------------------------------------------------------------------------
extern "C" void kernel_launch(void* const* d_in, const int* in_sizes, int n_in,
                              void* d_out, int out_size, void* d_ws, size_t ws_size,
                              hipStream_t stream) {
  const float* x  = (const float*)d_in[0];
  const float* Wq = (const float*)d_in[1];
  const float* bq = (const float*)d_in[2];
  const float* Wk = (const float*)d_in[3];
  const float* Wv = (const float*)d_in[4];
  const float* bv = (const float*)d_in[5];
  const float* Wo = (const float*)d_in[6];
  const float* bo = (const float*)d_in[7];
  float* out = (float*)d_out;

  // Per-batch workspace layout (bytes): same offsets as the proven 101.2 MB
  // layout (W3 region now only uses 12.6 of its 18.9 MB).
  const size_t REQUIRED = 101187584;
  if (ws_size < REQUIRED) return;  // clean failure instead of device fault

  char* w = (char*)d_ws;
  unsigned short* W3     = (unsigned short*)(w);                 // <= 18,874,368
  unsigned short* Wo3    = (unsigned short*)(w + 18874368);      //  6,291,456
  unsigned short* xT3b   = (unsigned short*)(w + 25165824);      // 25,165,824
  float*          qkvTb  = (float*)(w + 50331648);               // 50,331,648
  float*          partK  = (float*)(w + 100663296);              //    262,144
  float*          partKV = (float*)(w + 100925440);              //    262,144

  // 1) weight prep (once)
  conv_w_kernel<<<dim3(1024, 4), 256, 0, stream>>>(Wq, Wk, Wv, Wo, W3, Wo3);

  for (int b = 0; b < NB; ++b) {
    const float* xb = x + (size_t)b * C_ST * T_SEQ;
    float* outb = out + (size_t)b * C_ST * T_SEQ;
    // 2) x transpose + 2-term split (batch b)
    conv_x_kernel<<<dim3(T_SEQ / 64, C_ST / 64), 256, 0, stream>>>(xb, xT3b);
    // 3) fused QKV GEMM (K=2048): qkvTb[t][j] = sum_k xT3b[t][k] * W3[j][k]
    gemm_bt_kernel<<<dim3(K3 / 128, T_SEQ / 128), 256, 0, stream>>>(
        xT3b, W3, qkvTb, nullptr, T_SEQ, K3, K2);
    // 4) chunked scan (batch b); scan_c overwrites xT3b with [oh|ol|oh] (K3)
    scan_a_kernel<<<dim3(NCHUNK / 4, 16), 256, 0, stream>>>(qkvTb, bv, partK, partKV);
    scan_b_kernel<<<dim3(16), 64, 0, stream>>>(partK, partKV);
    scan_c_kernel<<<dim3(NCHUNK / 4, 16), 256, 0, stream>>>(qkvTb, bq, bv, partK, partKV, xT3b);
    // 5) output GEMM (K=3072): outb[o][t] = bo[o] + sum_k Wo3[o][k] * xT3b[t][k]
    gemm_bt_kernel<<<dim3(T_SEQ / 128, C_ST / 128), 256, 0, stream>>>(
        Wo3, xT3b, outb, bo, C_ST, T_SEQ, K3);
  }
}

// Round 13
// 581.096 us; speedup vs baseline: 2.6594x; 1.4765x over previous
//
#include <hip/hip_runtime.h>
#include <hip/hip_bf16.h>
#include <stdint.h>

#define T_SEQ 4096
#define C_ST  1024
#define K2    2048
#define K3    3072
#define NB    4
#define NCHUNK 128
#define CHUNK  32

typedef __bf16 bf16x8_t __attribute__((ext_vector_type(8)));
typedef float f32x4_t __attribute__((ext_vector_type(4)));
typedef unsigned short u16x8 __attribute__((ext_vector_type(8)));
typedef unsigned short u16x4 __attribute__((ext_vector_type(4)));
typedef __attribute__((address_space(1))) unsigned int as1u32;
typedef __attribute__((address_space(3))) unsigned int as3u32;

__device__ __forceinline__ unsigned short bfbits(float f) {
  __hip_bfloat16 h = __float2bfloat16(f);
  return *reinterpret_cast<unsigned short*>(&h);
}
__device__ __forceinline__ float bf2f(unsigned short u) {
  __hip_bfloat16 h;
  *reinterpret_cast<unsigned short*>(&h) = u;
  return __bfloat162float(h);
}
__device__ __forceinline__ float phi_f(float x) {
  // silu(x) + 1
  return x / (1.0f + __expf(-x)) + 1.0f;
}

// ---------------------------------------------------------------------------
// Weight prep: all four W (1024x1024 f32) -> rows of K2=2048 bf16: [Wh | Wh]
// (pairs with 2-term split activations [ah | al]: ah*Wh + al*Wh = a*Wh)
// ---------------------------------------------------------------------------
__global__ __launch_bounds__(256) void conv_w_kernel(
    const float* __restrict__ Wq, const float* __restrict__ Wk,
    const float* __restrict__ Wv, const float* __restrict__ Wo,
    unsigned short* __restrict__ W3, unsigned short* __restrict__ Wo3) {
  int r = blockIdx.x;
  int which = blockIdx.y;
  const float* src = (which == 0) ? Wq : (which == 1) ? Wk : (which == 2) ? Wv : Wo;
  unsigned short* dst = (which < 3) ? (W3 + (size_t)(which * 1024 + r) * K2)
                                    : (Wo3 + (size_t)r * K2);
  int c4 = threadIdx.x * 4;
  float4 v = *reinterpret_cast<const float4*>(&src[(size_t)r * 1024 + c4]);
  float fe[4] = {v.x, v.y, v.z, v.w};
  u16x4 hh;
#pragma unroll
  for (int e = 0; e < 4; ++e) hh[e] = bfbits(fe[e]);
  *reinterpret_cast<u16x4*>(&dst[c4])        = hh;
  *reinterpret_cast<u16x4*>(&dst[1024 + c4]) = hh;
}

// ---------------------------------------------------------------------------
// x prep: x (B,C,T) f32 -> xT (z,T,2C) bf16 [xh | xl]; grid (T/64, C/64, PB)
// ---------------------------------------------------------------------------
__global__ __launch_bounds__(256) void conv_x_kernel(
    const float* __restrict__ x0, unsigned short* __restrict__ xT0) {
  __shared__ float tile[64][65];
  int c0 = blockIdx.y * 64, t0 = blockIdx.x * 64, z = blockIdx.z;
  const float* xb = x0 + (size_t)z * C_ST * T_SEQ + (size_t)c0 * T_SEQ + t0;
  unsigned short* xT = xT0 + (size_t)z * T_SEQ * K2;
  int tid = threadIdx.x;
#pragma unroll
  for (int p = 0; p < 4; ++p) {
    int idx = tid + p * 256;
    int r = idx >> 4, q4 = (idx & 15) * 4;
    float4 v = *reinterpret_cast<const float4*>(&xb[(size_t)r * T_SEQ + q4]);
    tile[r][q4 + 0] = v.x; tile[r][q4 + 1] = v.y;
    tile[r][q4 + 2] = v.z; tile[r][q4 + 3] = v.w;
  }
  __syncthreads();
  int r = tid >> 2, q = (tid & 3) * 16;
  u16x8 h0, h1, l0, l1;
#pragma unroll
  for (int j = 0; j < 8; ++j) {
    float f = tile[q + j][r];
    unsigned short hb = bfbits(f);
    h0[j] = hb; l0[j] = bfbits(f - bf2f(hb));
  }
#pragma unroll
  for (int j = 0; j < 8; ++j) {
    float f = tile[q + 8 + j][r];
    unsigned short hb = bfbits(f);
    h1[j] = hb; l1[j] = bfbits(f - bf2f(hb));
  }
  unsigned short* dst = xT + ((size_t)(t0 + r)) * K2 + c0 + q;
  *reinterpret_cast<u16x8*>(dst)         = h0;
  *reinterpret_cast<u16x8*>(dst + 8)     = h1;
  *reinterpret_cast<u16x8*>(dst + 1024)  = l0;
  *reinterpret_cast<u16x8*>(dst + 1032)  = l1;
}

// ---------------------------------------------------------------------------
// gemm_bt: C[m][n] = sum_k A[m][k]*B[n][k] (+biasM[m]); z-batched via strides.
// 128x128 tile, BK=64, 4 waves (2x2), 16x16x32 MFMA, global_load_lds w16.
// Lane-permutation swizzle (proven r12): stage seg_src=(l&7)^((l>>3)&7),
// read seg = kseg^(row&7). Banks 2-way (free); staging contiguous.
// ---------------------------------------------------------------------------
__global__ __launch_bounds__(256) void gemm_bt_kernel(
    const unsigned short* __restrict__ A, const unsigned short* __restrict__ B,
    float* __restrict__ C, const float* __restrict__ biasM,
    int M, int N, int K, long long sA, long long sB, long long sC) {
  __shared__ unsigned short As[128 * 64];
  __shared__ unsigned short Bs[128 * 64];
  int z = blockIdx.z;
  const unsigned short* Ab = A + (size_t)z * sA;
  const unsigned short* Bb = B + (size_t)z * sB;
  float* Cb = C + (size_t)z * sC;
  int m0 = blockIdx.y * 128, n0 = blockIdx.x * 128;
  int tid = threadIdx.x, lane = tid & 63, wid = tid >> 6;
  int wr = wid >> 1, wc = wid & 1;
  int l16 = lane & 15, l4 = lane >> 4;
  int seg_src = (lane & 7) ^ ((lane >> 3) & 7);
  f32x4_t acc[4][4] = {};

  for (int k0 = 0; k0 < K; k0 += 64) {
    __syncthreads();
#pragma unroll
    for (int s = 0; s < 4; ++s) {
      int chunk = wid * 4 + s;              // 1KB = rows 8c..8c+7
      int row = chunk * 8 + (lane >> 3);
      const unsigned short* ga = Ab + (size_t)(m0 + row) * K + k0 + seg_src * 8;
      const unsigned short* gb = Bb + (size_t)(n0 + row) * K + k0 + seg_src * 8;
      __builtin_amdgcn_global_load_lds((as1u32*)ga, (as3u32*)(As + chunk * 512), 16, 0, 0);
      __builtin_amdgcn_global_load_lds((as1u32*)gb, (as3u32*)(Bs + chunk * 512), 16, 0, 0);
    }
    __syncthreads();
#pragma unroll
    for (int s2 = 0; s2 < 2; ++s2) {
      bf16x8_t af[4], bfr[4];
      int kseg = s2 * 4 + l4;
#pragma unroll
      for (int m = 0; m < 4; ++m) {
        int r = wr * 64 + m * 16 + l16;
        af[m] = *reinterpret_cast<const bf16x8_t*>(&As[r * 64 + (kseg ^ (r & 7)) * 8]);
      }
#pragma unroll
      for (int n = 0; n < 4; ++n) {
        int r = wc * 64 + n * 16 + l16;
        bfr[n] = *reinterpret_cast<const bf16x8_t*>(&Bs[r * 64 + (kseg ^ (r & 7)) * 8]);
      }
#pragma unroll
      for (int m = 0; m < 4; ++m)
#pragma unroll
        for (int n = 0; n < 4; ++n)
          acc[m][n] = __builtin_amdgcn_mfma_f32_16x16x32_bf16(af[m], bfr[n], acc[m][n], 0, 0, 0);
    }
  }

#pragma unroll
  for (int m = 0; m < 4; ++m) {
#pragma unroll
    for (int n = 0; n < 4; ++n) {
      int row = m0 + wr * 64 + m * 16 + l4 * 4;
      int col = n0 + wc * 64 + n * 16 + l16;
#pragma unroll
      for (int j = 0; j < 4; ++j) {
        float val = acc[m][n][j];
        if (biasM) val += biasM[row + j];
        Cb[(size_t)(row + j) * N + col] = val;
      }
    }
  }
}

// ---------------------------------------------------------------------------
// Scan A: per-chunk totals. grid (NCHUNK/4, 16, PB), 256 thr = 4 waves.
// ---------------------------------------------------------------------------
__global__ __launch_bounds__(256) void scan_a_kernel(
    const float* __restrict__ qkvT0, const float* __restrict__ bv,
    float* __restrict__ partK, float* __restrict__ partKV) {
  int d = threadIdx.x & 63;
  int w = threadIdx.x >> 6;
  int ch = blockIdx.x * 4 + w, h = blockIdx.y, z = blockIdx.z;
  int c = h * 64 + d;
  float bvc = bv[c];
  const float* base = qkvT0 + (size_t)z * T_SEQ * K3 + (size_t)ch * CHUNK * K3;
  float sk = 0.f, skv = 0.f;
  for (int tt = 0; tt < CHUNK; tt += 4) {
    float kv[4], vv[4];
#pragma unroll
    for (int u = 0; u < 4; ++u) {
      const float* row = base + (size_t)(tt + u) * K3;
      kv[u] = row[1024 + c];
      vv[u] = row[2048 + c];
    }
#pragma unroll
    for (int u = 0; u < 4; ++u) {
      float pk = phi_f(kv[u]);
      sk += pk; skv += pk * (vv[u] + bvc);
    }
  }
  size_t pidx = (((size_t)z * 16 + h) * NCHUNK + ch) * 64 + d;
  partK[pidx] = sk;
  partKV[pidx] = skv;
}

// Scan B: exclusive prefix over chunks. grid (16, PB), 64 threads.
__global__ void scan_b_kernel(float* __restrict__ partK, float* __restrict__ partKV) {
  int d = threadIdx.x;
  int h = blockIdx.x, z = blockIdx.y;
  size_t base = ((size_t)z * 16 + h) * NCHUNK * 64 + d;
  float rk = 0.f, rkv = 0.f;
  for (int ch = 0; ch < NCHUNK; ++ch) {
    size_t i = base + (size_t)ch * 64;
    float tk = partK[i], tkv = partKV[i];
    partK[i] = rk; partKV[i] = rkv;
    rk += tk; rkv += tkv;
  }
}

// Scan C: emit attention output, 2-term split [oh | ol] (K2 stride).
// grid (NCHUNK/4, 16, PB), 256 thr = 4 waves.
__global__ __launch_bounds__(256) void scan_c_kernel(
    const float* __restrict__ qkvT0,
    const float* __restrict__ bq, const float* __restrict__ bv,
    const float* __restrict__ partK, const float* __restrict__ partKV,
    unsigned short* __restrict__ outT0) {
  int d = threadIdx.x & 63;
  int w = threadIdx.x >> 6;
  int ch = blockIdx.x * 4 + w, h = blockIdx.y, z = blockIdx.z;
  int c = h * 64 + d;
  size_t pidx = (((size_t)z * 16 + h) * NCHUNK + ch) * 64 + d;
  float sk = partK[pidx], skv = partKV[pidx];
  float bqc = bq[c], bvc = bv[c];
  const float* base = qkvT0 + (size_t)z * T_SEQ * K3 + (size_t)ch * CHUNK * K3;
  unsigned short* obase = outT0 + (size_t)z * T_SEQ * K2 + (size_t)ch * CHUNK * K2;
  for (int tt = 0; tt < CHUNK; tt += 4) {
    float qv[4], kv[4], vv[4];
#pragma unroll
    for (int u = 0; u < 4; ++u) {
      const float* row = base + (size_t)(tt + u) * K3;
      qv[u] = row[c];
      kv[u] = row[1024 + c];
      vv[u] = row[2048 + c];
    }
    float pq[4], dp[4], skv_s[4];
#pragma unroll
    for (int u = 0; u < 4; ++u) {
      pq[u] = phi_f(qv[u] + bqc);
      float pk = phi_f(kv[u]);
      sk += pk; skv += pk * (vv[u] + bvc);
      dp[u] = pq[u] * sk;
      skv_s[u] = skv;
    }
#pragma unroll
    for (int off = 32; off > 0; off >>= 1)
#pragma unroll
      for (int u = 0; u < 4; ++u) dp[u] += __shfl_xor(dp[u], off);
#pragma unroll
    for (int u = 0; u < 4; ++u) {
      float o = pq[u] * skv_s[u] / (dp[u] + 1e-6f) * 0.125f;  // 1/sqrt(64)
      unsigned short oh = bfbits(o);
      unsigned short ol = bfbits(o - bf2f(oh));
      unsigned short* orow = obase + (size_t)(tt + u) * K2;
      orow[c] = oh; orow[1024 + c] = ol;
    }
  }
}

// ---------------------------------------------------------------------------
extern "C" void kernel_launch(void* const* d_in, const int* in_sizes, int n_in,
                              void* d_out, int out_size, void* d_ws, size_t ws_size,
                              hipStream_t stream) {
  const float* x  = (const float*)d_in[0];
  const float* Wq = (const float*)d_in[1];
  const float* bq = (const float*)d_in[2];
  const float* Wk = (const float*)d_in[3];
  const float* Wv = (const float*)d_in[4];
  const float* bv = (const float*)d_in[5];
  const float* Wo = (const float*)d_in[6];
  const float* bo = (const float*)d_in[7];
  float* out = (float*)d_out;

  // Workspace layout (generic in PB = batches pipelined per dispatch group):
  //   W3   @ 0                  : 3*1024*K2*2 = 12,582,912
  //   Wo3  @ 12,582,912         : 1024*K2*2  =  4,194,304
  //   xT   @ 16,777,216         : PB * 16,777,216   (T*K2 bf16; also outT)
  //   qkvT @ 16,777,216+PB*xT   : PB * 50,331,648   (T*K3 f32)
  //   partK/partKV              : PB * 524,288 each
  const size_t BASE = 16777216;
  const size_t PER  = 16777216ULL + 50331648ULL + 2 * 524288ULL;  // 67.9 MB
  int PB = (ws_size >= BASE + 4 * PER) ? 4 : (ws_size >= BASE + 2 * PER) ? 2
         : (ws_size >= BASE + 1 * PER) ? 1 : 0;
  if (PB == 0) return;  // clean failure instead of device fault

  char* w = (char*)d_ws;
  unsigned short* W3     = (unsigned short*)(w);
  unsigned short* Wo3    = (unsigned short*)(w + 12582912);
  unsigned short* xT     = (unsigned short*)(w + BASE);
  float*          qkvT   = (float*)(w + BASE + (size_t)PB * 16777216);
  float*          partK  = (float*)(w + BASE + (size_t)PB * 67108864);
  float*          partKV = (float*)(w + BASE + (size_t)PB * 67108864 + (size_t)PB * 524288);

  // 1) weight prep (once)
  conv_w_kernel<<<dim3(1024, 4), 256, 0, stream>>>(Wq, Wk, Wv, Wo, W3, Wo3);

  for (int g = 0; g < NB; g += PB) {
    const float* xg = x + (size_t)g * C_ST * T_SEQ;
    float* outg = out + (size_t)g * C_ST * T_SEQ;
    // 2) x transpose + 2-term split (PB batches)
    conv_x_kernel<<<dim3(T_SEQ / 64, C_ST / 64, PB), 256, 0, stream>>>(xg, xT);
    // 3) fused QKV GEMM (K=2048): qkvT[z][t][j] = sum_k xT[z][t][k]*W3[j][k]
    gemm_bt_kernel<<<dim3(K3 / 128, T_SEQ / 128, PB), 256, 0, stream>>>(
        xT, W3, qkvT, nullptr, T_SEQ, K3, K2,
        (long long)T_SEQ * K2, 0LL, (long long)T_SEQ * K3);
    // 4) chunked scan; scan_c writes [oh|ol] into xT (dead after GEMM1)
    scan_a_kernel<<<dim3(NCHUNK / 4, 16, PB), 256, 0, stream>>>(qkvT, bv, partK, partKV);
    scan_b_kernel<<<dim3(16, PB), 64, 0, stream>>>(partK, partKV);
    scan_c_kernel<<<dim3(NCHUNK / 4, 16, PB), 256, 0, stream>>>(qkvT, bq, bv, partK, partKV, xT);
    // 5) output GEMM (K=2048): outg[z][o][t] = bo[o] + sum_k Wo3[o][k]*xT[z][t][k]
    gemm_bt_kernel<<<dim3(T_SEQ / 128, C_ST / 128, PB), 256, 0, stream>>>(
        Wo3, xT, outg, bo, C_ST, T_SEQ, K2,
        0LL, (long long)T_SEQ * K2, (long long)C_ST * T_SEQ);
  }
}